// Round 1
// baseline (605.564 us; speedup 1.0000x reference)
//
#include <hip/hip_runtime.h>
#include <hip/hip_bf16.h>

typedef __attribute__((ext_vector_type(8))) short short8;
typedef __attribute__((ext_vector_type(4))) float f32x4;

#define BATCH 4
#define TLEN 4096
#define CDIM 1024
#define HSD 128
#define MROWS (BATCH*TLEN)

__device__ __forceinline__ unsigned short f2bf(float f){
    unsigned u = __builtin_bit_cast(unsigned, f);
    u = (u + 0x7FFFu + ((u >> 16) & 1u)) >> 16;
    return (unsigned short)u;
}

// ---------------- kernel 1: W (C,HS) fp32 -> Wt (3,HS,C) bf16 ----------------
__global__ void prep_w_k(const float* __restrict__ Wq, const float* __restrict__ Wk,
                         const float* __restrict__ Wv, unsigned short* __restrict__ Wt){
    int idx = blockIdx.x * 256 + threadIdx.x;
    const int total = 3 * HSD * CDIM;
    if (idx >= total) return;
    int w = idx / (HSD * CDIM);
    int r = idx - w * HSD * CDIM;
    int h = r / CDIM;
    int c = r - h * CDIM;
    const float* W = (w == 0) ? Wq : ((w == 1) ? Wk : Wv);
    Wt[idx] = f2bf(W[c * HSD + h]);
}

// ---------------- kernel 2: projection x(M,C) @ W -> Q,K (M,HS) bf16, Vt (B,HS,T) bf16
// one wave per block; block computes 16 rows x 128 cols of one projection.
__global__ void proj_k(const float* __restrict__ x, const unsigned short* __restrict__ Wt,
                       unsigned short* __restrict__ Qb, unsigned short* __restrict__ Kb,
                       unsigned short* __restrict__ Vt){
    const int lane = threadIdx.x;
    const int m = lane & 15, quad = lane >> 4;
    const int rb = blockIdx.x * 16;
    const int p = blockIdx.y;
    const unsigned short* W = Wt + (size_t)p * HSD * CDIM;

    f32x4 acc[8];
#pragma unroll
    for (int i = 0; i < 8; i++) acc[i] = (f32x4)0.f;

    const float* xrow = x + (size_t)(rb + m) * CDIM + quad * 8;
    for (int k0 = 0; k0 < CDIM; k0 += 32){
        float4 a0 = *(const float4*)(xrow + k0);
        float4 a1 = *(const float4*)(xrow + k0 + 4);
        short8 aF;
        aF[0] = (short)f2bf(a0.x); aF[1] = (short)f2bf(a0.y);
        aF[2] = (short)f2bf(a0.z); aF[3] = (short)f2bf(a0.w);
        aF[4] = (short)f2bf(a1.x); aF[5] = (short)f2bf(a1.y);
        aF[6] = (short)f2bf(a1.z); aF[7] = (short)f2bf(a1.w);
#pragma unroll
        for (int sub = 0; sub < 8; sub++){
            short8 bF = *(const short8*)(W + (size_t)(sub * 16 + m) * CDIM + k0 + quad * 8);
            acc[sub] = __builtin_amdgcn_mfma_f32_16x16x32_bf16(aF, bF, acc[sub], 0, 0, 0);
        }
    }
#pragma unroll
    for (int sub = 0; sub < 8; sub++){
#pragma unroll
        for (int r = 0; r < 4; r++){
            int row = rb + quad * 4 + r;           // global M row
            int col = sub * 16 + m;                // head dim
            unsigned short v = f2bf(acc[sub][r]);
            if (p == 0)      Qb[(size_t)row * HSD + col] = v;
            else if (p == 1) Kb[(size_t)row * HSD + col] = v;
            else {
                int b = row >> 12;                 // /4096
                int t = row & 4095;
                Vt[((size_t)b * HSD + col) * TLEN + t] = v;
            }
        }
    }
}

// ---------------- kernel 3: causal flash attention, one wave per 16 query rows
__global__ void attn_k(const unsigned short* __restrict__ Qb, const unsigned short* __restrict__ Kb,
                       const unsigned short* __restrict__ Vt, float* __restrict__ out){
    __shared__ unsigned short Pl[16 * 72];   // 16 rows x 64 cols, padded to 72 (2-way bank alias = free)
    const int lane = threadIdx.x;
    const int m = lane & 15, quad = lane >> 4;
    const int qb = blockIdx.x * 16;          // query tile start (within batch)
    const int b  = blockIdx.y;
    const size_t row0 = (size_t)b * TLEN + qb;
    const float scale = 0.08838834764831845f; // 1/sqrt(128)

    // Q fragments: A[m=lane&15][k=quad*8+j], 4 k-steps of 32
    short8 aQ[4];
#pragma unroll
    for (int kk = 0; kk < 4; kk++)
        aQ[kk] = *(const short8*)(Qb + (row0 + m) * HSD + kk * 32 + quad * 8);

    f32x4 accO[8];
#pragma unroll
    for (int i = 0; i < 8; i++) accO[i] = (f32x4)0.f;
    float mi[4], li[4];
#pragma unroll
    for (int r = 0; r < 4; r++){ mi[r] = -1e30f; li[r] = 0.f; }

    const unsigned short* kbb = Kb + (size_t)b * TLEN * HSD;
    const unsigned short* vbb = Vt + (size_t)b * HSD * TLEN;

    const int nT = (qb + 15) / 64 + 1;
    for (int tile = 0; tile < nT; ++tile){
        const int s0 = tile * 64;
        // ---- S = Q K^T (16x64), 4 n-subtiles
        f32x4 S[4];
#pragma unroll
        for (int ns = 0; ns < 4; ns++){
            f32x4 sa = (f32x4)0.f;
            const unsigned short* kbase = kbb + (size_t)(s0 + ns * 16 + m) * HSD + quad * 8;
#pragma unroll
            for (int kk = 0; kk < 4; kk++){
                short8 bK = *(const short8*)(kbase + kk * 32);
                sa = __builtin_amdgcn_mfma_f32_16x16x32_bf16(aQ[kk], bK, sa, 0, 0, 0);
            }
#pragma unroll
            for (int r = 0; r < 4; r++) sa[r] *= scale;
            S[ns] = sa;
        }
        // ---- causal mask (only boundary tile needs it)
        if (s0 + 63 > qb){
#pragma unroll
            for (int ns = 0; ns < 4; ns++){
                int sg = s0 + ns * 16 + m;      // key index (col)
#pragma unroll
                for (int r = 0; r < 4; r++){
                    int qrow = qb + quad * 4 + r;
                    if (sg > qrow) S[ns][r] = -1e30f;
                }
            }
        }
        // ---- online softmax: row max across 16 lanes of the quad
        float mloc[4];
#pragma unroll
        for (int r = 0; r < 4; r++)
            mloc[r] = fmaxf(fmaxf(S[0][r], S[1][r]), fmaxf(S[2][r], S[3][r]));
#pragma unroll
        for (int off = 1; off < 16; off <<= 1){
#pragma unroll
            for (int r = 0; r < 4; r++)
                mloc[r] = fmaxf(mloc[r], __shfl_xor(mloc[r], off, 64));
        }
        float al[4];
#pragma unroll
        for (int r = 0; r < 4; r++){
            float mn = fmaxf(mi[r], mloc[r]);
            al[r] = __expf(mi[r] - mn);
            mi[r] = mn;
        }
        // ---- P = exp(S - m), accumulate row sums, write P (bf16) to LDS in C-layout
        float lsum[4] = {0.f, 0.f, 0.f, 0.f};
#pragma unroll
        for (int ns = 0; ns < 4; ns++){
#pragma unroll
            for (int r = 0; r < 4; r++){
                float pv = __expf(S[ns][r] - mi[r]);
                lsum[r] += pv;
                Pl[(quad * 4 + r) * 72 + ns * 16 + m] = f2bf(pv);
            }
        }
#pragma unroll
        for (int off = 1; off < 16; off <<= 1){
#pragma unroll
            for (int r = 0; r < 4; r++)
                lsum[r] += __shfl_xor(lsum[r], off, 64);
        }
#pragma unroll
        for (int r = 0; r < 4; r++) li[r] = li[r] * al[r] + lsum[r];
        // ---- rescale O
#pragma unroll
        for (int sub = 0; sub < 8; sub++)
#pragma unroll
            for (int r = 0; r < 4; r++) accO[sub][r] *= al[r];
        // ---- read P back in A-layout (compiler inserts lgkmcnt waits for the dependence)
        short8 aP[2];
#pragma unroll
        for (int t = 0; t < 2; t++)
            aP[t] = *(const short8*)(Pl + m * 72 + t * 32 + quad * 8);
        // ---- O += P V  (V^T stored so B-frag is contiguous along s)
#pragma unroll
        for (int sub = 0; sub < 8; sub++){
#pragma unroll
            for (int t = 0; t < 2; t++){
                short8 bV = *(const short8*)(vbb + (size_t)(sub * 16 + m) * TLEN + s0 + t * 32 + quad * 8);
                accO[sub] = __builtin_amdgcn_mfma_f32_16x16x32_bf16(aP[t], bV, accO[sub], 0, 0, 0);
            }
        }
    }
    // ---- epilogue: out = O / l  (fp32, row-major B,T,HS)
    float inv[4];
#pragma unroll
    for (int r = 0; r < 4; r++) inv[r] = 1.0f / li[r];
#pragma unroll
    for (int sub = 0; sub < 8; sub++){
#pragma unroll
        for (int r = 0; r < 4; r++){
            out[(row0 + quad * 4 + r) * HSD + sub * 16 + m] = accO[sub][r] * inv[r];
        }
    }
}

extern "C" void kernel_launch(void* const* d_in, const int* in_sizes, int n_in,
                              void* d_out, int out_size, void* d_ws, size_t ws_size,
                              hipStream_t stream) {
    const float* x  = (const float*)d_in[0];
    const float* Wq = (const float*)d_in[1];
    const float* Wk = (const float*)d_in[2];
    const float* Wv = (const float*)d_in[3];
    float* out = (float*)d_out;

    // workspace layout (bytes): Wt @0 (768K), Qb @1M (4M), Kb @5M (4M), Vt @9M (4M)
    unsigned short* Wt = (unsigned short*)d_ws;
    unsigned short* Qb = (unsigned short*)((char*)d_ws + (1u << 20));
    unsigned short* Kb = (unsigned short*)((char*)d_ws + (5u << 20));
    unsigned short* Vt = (unsigned short*)((char*)d_ws + (9u << 20));

    prep_w_k<<<(3 * HSD * CDIM + 255) / 256, 256, 0, stream>>>(Wq, Wk, Wv, Wt);
    proj_k<<<dim3(MROWS / 16, 3), 64, 0, stream>>>(x, Wt, Qb, Kb, Vt);
    attn_k<<<dim3(TLEN / 16, BATCH), 64, 0, stream>>>(Qb, Kb, Vt, out);
}

// Round 2
// 323.709 us; speedup vs baseline: 1.8707x; 1.8707x over previous
//
#include <hip/hip_runtime.h>
#include <hip/hip_bf16.h>

typedef __attribute__((ext_vector_type(8))) short short8;
typedef __attribute__((ext_vector_type(4))) float f32x4;

#define BATCH 4
#define TLEN 4096
#define CDIM 1024
#define HSD 128
#define MROWS (BATCH*TLEN)

__device__ __forceinline__ unsigned short f2bf(float f){
    unsigned u = __builtin_bit_cast(unsigned, f);
    u = (u + 0x7FFFu + ((u >> 16) & 1u)) >> 16;
    return (unsigned short)u;
}

// ---------------- kernel 1: W (C,HS) fp32 -> Wt (3,HS,C) bf16 ----------------
__global__ void prep_w_k(const float* __restrict__ Wq, const float* __restrict__ Wk,
                         const float* __restrict__ Wv, unsigned short* __restrict__ Wt){
    int idx = blockIdx.x * 256 + threadIdx.x;
    const int total = 3 * HSD * CDIM;
    if (idx >= total) return;
    int w = idx / (HSD * CDIM);
    int r = idx - w * HSD * CDIM;
    int h = r / CDIM;
    int c = r - h * CDIM;
    const float* W = (w == 0) ? Wq : ((w == 1) ? Wk : Wv);
    Wt[idx] = f2bf(W[c * HSD + h]);
}

// ---------------- kernel 1b: x fp32 -> bf16 ----------------
__global__ void prep_x_k(const float* __restrict__ x, unsigned short* __restrict__ xb){
    int i = (blockIdx.x * 256 + threadIdx.x) * 8;
    float4 a = *(const float4*)(x + i);
    float4 b = *(const float4*)(x + i + 4);
    short8 o;
    o[0]=(short)f2bf(a.x); o[1]=(short)f2bf(a.y); o[2]=(short)f2bf(a.z); o[3]=(short)f2bf(a.w);
    o[4]=(short)f2bf(b.x); o[5]=(short)f2bf(b.y); o[6]=(short)f2bf(b.z); o[7]=(short)f2bf(b.w);
    *(short8*)(xb + i) = o;
}

// ---------------- projection epilogue helper ----------------
__device__ __forceinline__ void proj_store(int p, int rb, int m, int quad, const f32x4* acc,
                                           unsigned short* __restrict__ Qb,
                                           unsigned short* __restrict__ Kb,
                                           unsigned short* __restrict__ Vt){
#pragma unroll
    for (int sub = 0; sub < 8; sub++){
#pragma unroll
        for (int r = 0; r < 4; r++){
            int row = rb + quad * 4 + r;
            int col = sub * 16 + m;
            unsigned short v = f2bf(acc[sub][r]);
            if (p == 0)      Qb[(size_t)row * HSD + col] = v;
            else if (p == 1) Kb[(size_t)row * HSD + col] = v;
            else {
                int b = row >> 12;
                int t = row & 4095;
                Vt[((size_t)b * HSD + col) * TLEN + t] = v;
            }
        }
    }
}

// ---------------- kernel 2a: fused projection from bf16 x ----------------
__global__ void proj_bf_k(const unsigned short* __restrict__ xb, const unsigned short* __restrict__ Wt,
                          unsigned short* __restrict__ Qb, unsigned short* __restrict__ Kb,
                          unsigned short* __restrict__ Vt){
    const int lane = threadIdx.x;
    const int m = lane & 15, quad = lane >> 4;
    const int rb = blockIdx.x * 16;

    f32x4 acc[3][8];
#pragma unroll
    for (int p = 0; p < 3; p++)
#pragma unroll
        for (int i = 0; i < 8; i++) acc[p][i] = (f32x4)0.f;

    const unsigned short* xrow = xb + (size_t)(rb + m) * CDIM + quad * 8;
    for (int k0 = 0; k0 < CDIM; k0 += 32){
        short8 aF = *(const short8*)(xrow + k0);
#pragma unroll
        for (int p = 0; p < 3; p++){
#pragma unroll
            for (int sub = 0; sub < 8; sub++){
                short8 bF = *(const short8*)(Wt + (size_t)(p * HSD + sub * 16 + m) * CDIM + k0 + quad * 8);
                acc[p][sub] = __builtin_amdgcn_mfma_f32_16x16x32_bf16(aF, bF, acc[p][sub], 0, 0, 0);
            }
        }
    }
#pragma unroll
    for (int p = 0; p < 3; p++) proj_store(p, rb, m, quad, acc[p], Qb, Kb, Vt);
}

// ---------------- kernel 2b: fused projection from fp32 x (ws fallback) ----------------
__global__ void proj_f32_k(const float* __restrict__ x, const unsigned short* __restrict__ Wt,
                           unsigned short* __restrict__ Qb, unsigned short* __restrict__ Kb,
                           unsigned short* __restrict__ Vt){
    const int lane = threadIdx.x;
    const int m = lane & 15, quad = lane >> 4;
    const int rb = blockIdx.x * 16;

    f32x4 acc[3][8];
#pragma unroll
    for (int p = 0; p < 3; p++)
#pragma unroll
        for (int i = 0; i < 8; i++) acc[p][i] = (f32x4)0.f;

    const float* xrow = x + (size_t)(rb + m) * CDIM + quad * 8;
    for (int k0 = 0; k0 < CDIM; k0 += 32){
        float4 a0 = *(const float4*)(xrow + k0);
        float4 a1 = *(const float4*)(xrow + k0 + 4);
        short8 aF;
        aF[0]=(short)f2bf(a0.x); aF[1]=(short)f2bf(a0.y); aF[2]=(short)f2bf(a0.z); aF[3]=(short)f2bf(a0.w);
        aF[4]=(short)f2bf(a1.x); aF[5]=(short)f2bf(a1.y); aF[6]=(short)f2bf(a1.z); aF[7]=(short)f2bf(a1.w);
#pragma unroll
        for (int p = 0; p < 3; p++){
#pragma unroll
            for (int sub = 0; sub < 8; sub++){
                short8 bF = *(const short8*)(Wt + (size_t)(p * HSD + sub * 16 + m) * CDIM + k0 + quad * 8);
                acc[p][sub] = __builtin_amdgcn_mfma_f32_16x16x32_bf16(aF, bF, acc[p][sub], 0, 0, 0);
            }
        }
    }
#pragma unroll
    for (int p = 0; p < 3; p++) proj_store(p, rb, m, quad, acc[p], Qb, Kb, Vt);
}

// ---------------- LDS staging (global_load_lds width 16, XOR-swizzled) ----------------
// K tile: 64 rows x 128 shorts (256 B/row, 16 chunks of 16B). chunk' = chunk ^ (row&15).
__device__ __forceinline__ void stage_k_tile(unsigned short* buf, const unsigned short* g,
                                             int wave, int lane){
#pragma unroll
    for (int i = 0; i < 4; i++){
        int slot = wave * 256 + i * 64 + lane;
        int row = slot >> 4;
        int ch  = slot & 15;
        const unsigned short* gp = g + row * 128 + ((ch ^ (row & 15)) << 3);
        unsigned short* lp = buf + ((wave * 256 + i * 64) << 3);
        __builtin_amdgcn_global_load_lds((const __attribute__((address_space(1))) void*)gp,
                                         (__attribute__((address_space(3))) void*)lp, 16, 0, 0);
    }
}
// V tile: 128 rows x 64 shorts (128 B/row, 8 chunks). row stride in global = TLEN. chunk' = chunk ^ (row&7).
__device__ __forceinline__ void stage_v_tile(unsigned short* buf, const unsigned short* g,
                                             int wave, int lane){
#pragma unroll
    for (int i = 0; i < 4; i++){
        int slot = wave * 256 + i * 64 + lane;
        int row = slot >> 3;
        int ch  = slot & 7;
        const unsigned short* gp = g + (size_t)row * TLEN + ((ch ^ (row & 7)) << 3);
        unsigned short* lp = buf + ((wave * 256 + i * 64) << 3);
        __builtin_amdgcn_global_load_lds((const __attribute__((address_space(1))) void*)gp,
                                         (__attribute__((address_space(3))) void*)lp, 16, 0, 0);
    }
}

// ---------------- kernel 3: causal flash attention, split-K partials ----------------
// grid: (T/64, nseg, B), block 256 (4 waves). Wave w owns query rows q0+16w..+15.
__global__ __launch_bounds__(256) void attn_k(const unsigned short* __restrict__ Qb,
                       const unsigned short* __restrict__ Kb,
                       const unsigned short* __restrict__ Vts,
                       float* __restrict__ Opart, float2* __restrict__ ml, int seglen){
    __shared__ unsigned short Kt[2][64 * 128];
    __shared__ unsigned short Vs[2][128 * 64];
    __shared__ unsigned short Pl[4][16 * 72];

    const int tid = threadIdx.x, lane = tid & 63, wave = tid >> 6;
    const int m = lane & 15, quad = lane >> 4;
    const int q0 = blockIdx.x * 64;
    const int seg = blockIdx.y, b = blockIdx.z;
    const int g0 = seg * seglen;
    if (g0 >= q0 + 64) return;                 // segment entirely in the causal future
    const int gend = min(g0 + seglen, q0 + 64);
    const int nT = (gend - g0) >> 6;
    const float scale = 0.08838834764831845f;  // 1/sqrt(128)

    const size_t rowg = (size_t)b * TLEN + q0 + wave * 16;   // wave's first global M row

    short8 aQ[4];
#pragma unroll
    for (int kk = 0; kk < 4; kk++)
        aQ[kk] = *(const short8*)(Qb + (rowg + m) * HSD + kk * 32 + quad * 8);

    f32x4 accO[8];
#pragma unroll
    for (int i = 0; i < 8; i++) accO[i] = (f32x4)0.f;
    float mi[4], li[4];
#pragma unroll
    for (int r = 0; r < 4; r++){ mi[r] = -1e30f; li[r] = 0.f; }

    const unsigned short* kbase = Kb + (size_t)b * TLEN * HSD;
    const unsigned short* vbase = Vts + (size_t)b * HSD * TLEN;

    stage_k_tile(&Kt[0][0], kbase + (size_t)g0 * HSD, wave, lane);
    stage_v_tile(&Vs[0][0], vbase + g0, wave, lane);
    __syncthreads();

    int cur = 0;
    for (int t = 0; t < nT; ++t){
        const int s0 = g0 + t * 64;
        if (t + 1 < nT){
            stage_k_tile(&Kt[cur ^ 1][0], kbase + (size_t)(s0 + 64) * HSD, wave, lane);
            stage_v_tile(&Vs[cur ^ 1][0], vbase + (s0 + 64), wave, lane);
        }
        // ---- S = Q K^T (16x64)
        f32x4 S[4];
#pragma unroll
        for (int ns = 0; ns < 4; ns++){
            f32x4 sa = (f32x4)0.f;
#pragma unroll
            for (int kk = 0; kk < 4; kk++){
                short8 bK = *(const short8*)&Kt[cur][(ns * 16 + m) * 128 + (((kk * 4 + quad) ^ m) << 3)];
                sa = __builtin_amdgcn_mfma_f32_16x16x32_bf16(aQ[kk], bK, sa, 0, 0, 0);
            }
#pragma unroll
            for (int r = 0; r < 4; r++) sa[r] *= scale;
            S[ns] = sa;
        }
        // ---- causal mask on boundary tiles (wave's lowest row = q0+16*wave)
        if (s0 + 63 > q0 + wave * 16){
#pragma unroll
            for (int ns = 0; ns < 4; ns++){
                int sg = s0 + ns * 16 + m;
#pragma unroll
                for (int r = 0; r < 4; r++){
                    int qrow = q0 + wave * 16 + quad * 4 + r;
                    if (sg > qrow) S[ns][r] = -1e30f;
                }
            }
        }
        // ---- online softmax
        float mloc[4];
#pragma unroll
        for (int r = 0; r < 4; r++)
            mloc[r] = fmaxf(fmaxf(S[0][r], S[1][r]), fmaxf(S[2][r], S[3][r]));
#pragma unroll
        for (int off = 1; off < 16; off <<= 1)
#pragma unroll
            for (int r = 0; r < 4; r++)
                mloc[r] = fmaxf(mloc[r], __shfl_xor(mloc[r], off, 64));
        float al[4];
#pragma unroll
        for (int r = 0; r < 4; r++){
            float mn = fmaxf(mi[r], mloc[r]);
            al[r] = __expf(mi[r] - mn);
            mi[r] = mn;
        }
        float lsum[4] = {0.f, 0.f, 0.f, 0.f};
#pragma unroll
        for (int ns = 0; ns < 4; ns++){
#pragma unroll
            for (int r = 0; r < 4; r++){
                float pv = __expf(S[ns][r] - mi[r]);
                lsum[r] += pv;
                Pl[wave][(quad * 4 + r) * 72 + ns * 16 + m] = f2bf(pv);
            }
        }
#pragma unroll
        for (int off = 1; off < 16; off <<= 1)
#pragma unroll
            for (int r = 0; r < 4; r++)
                lsum[r] += __shfl_xor(lsum[r], off, 64);
#pragma unroll
        for (int r = 0; r < 4; r++) li[r] = li[r] * al[r] + lsum[r];
#pragma unroll
        for (int sub = 0; sub < 8; sub++)
#pragma unroll
            for (int r = 0; r < 4; r++) accO[sub][r] *= al[r];
        // ---- P back in A-layout (per-wave private LDS; compiler inserts lgkmcnt)
        short8 aP[2];
#pragma unroll
        for (int t2 = 0; t2 < 2; t2++)
            aP[t2] = *(const short8*)&Pl[wave][m * 72 + t2 * 32 + quad * 8];
        // ---- O += P V from swizzled LDS V tile
#pragma unroll
        for (int sub = 0; sub < 8; sub++){
#pragma unroll
            for (int t2 = 0; t2 < 2; t2++){
                short8 bV = *(const short8*)&Vs[cur][(sub * 16 + m) * 64 + (((t2 * 4 + quad) ^ (m & 7)) << 3)];
                accO[sub] = __builtin_amdgcn_mfma_f32_16x16x32_bf16(aP[t2], bV, accO[sub], 0, 0, 0);
            }
        }
        __syncthreads();   // reads of cur done + prefetch vmcnt drained
        cur ^= 1;
    }
    // ---- epilogue: unnormalized partial O + (m,l) per row
    if (m == 0){
#pragma unroll
        for (int r = 0; r < 4; r++){
            float2 v; v.x = mi[r]; v.y = li[r];
            ml[(size_t)seg * MROWS + rowg + quad * 4 + r] = v;
        }
    }
    float* ob = Opart + (size_t)seg * MROWS * HSD;
#pragma unroll
    for (int sub = 0; sub < 8; sub++)
#pragma unroll
        for (int r = 0; r < 4; r++)
            ob[(rowg + quad * 4 + r) * HSD + sub * 16 + m] = accO[sub][r];
}

// ---------------- kernel 4: merge split-K partials ----------------
__global__ void merge_k(const float* __restrict__ Opart, const float2* __restrict__ ml,
                        float* __restrict__ out, int nseg, int seglen){
    int idx = blockIdx.x * 256 + threadIdx.x;   // over MROWS*HSD
    int row = idx >> 7;
    int t = row & (TLEN - 1);
    int q0 = t & ~63;
    int nsv = min(nseg, (q0 + 63) / seglen + 1);
    float M = -1e30f;
    for (int s = 0; s < nsv; s++) M = fmaxf(M, ml[(size_t)s * MROWS + row].x);
    float L = 0.f, o = 0.f;
    for (int s = 0; s < nsv; s++){
        float2 p = ml[(size_t)s * MROWS + row];
        float w = __expf(p.x - M);
        L += p.y * w;
        o += w * Opart[(size_t)s * MROWS * HSD + idx];
    }
    out[idx] = o / L;
}

extern "C" void kernel_launch(void* const* d_in, const int* in_sizes, int n_in,
                              void* d_out, int out_size, void* d_ws, size_t ws_size,
                              hipStream_t stream) {
    const float* x  = (const float*)d_in[0];
    const float* Wq = (const float*)d_in[1];
    const float* Wk = (const float*)d_in[2];
    const float* Wv = (const float*)d_in[3];
    float* out = (float*)d_out;
    char* w = (char*)d_ws;

    unsigned short* Wt = (unsigned short*)w;    // 768 KB @ 0
    unsigned short *xb = nullptr, *Qb, *Kb, *Vt;
    float* Opart; float2* ml;
    int nseg; bool use_xb;

    if (ws_size >= (size_t)78u * 1024 * 1024){
        // full config: split-K=4 + bf16 x
        nseg = 4; use_xb = true;
        xb = (unsigned short*)(w + ((size_t)1u  << 20));
        Qb = (unsigned short*)(w + ((size_t)33u << 20));
        Kb = (unsigned short*)(w + ((size_t)37u << 20));
        Vt = (unsigned short*)(w + ((size_t)41u << 20));
        Opart = (float*)(w + ((size_t)45u << 20));
        ml    = (float2*)(w + ((size_t)77u << 20));
    } else if (ws_size >= (size_t)46u * 1024 * 1024){
        nseg = 1; use_xb = true;
        xb = (unsigned short*)(w + ((size_t)1u  << 20));
        Qb = (unsigned short*)(w + ((size_t)33u << 20));
        Kb = (unsigned short*)(w + ((size_t)37u << 20));
        Vt = (unsigned short*)(w + ((size_t)41u << 20));
        Opart = out;
        ml    = (float2*)(w + ((size_t)45u << 20));
    } else {
        nseg = 1; use_xb = false;
        Qb = (unsigned short*)(w + ((size_t)1u << 20));
        Kb = (unsigned short*)(w + ((size_t)5u << 20));
        Vt = (unsigned short*)(w + ((size_t)9u << 20));
        Opart = out;
        ml    = (float2*)(w + ((size_t)13u << 20));
    }
    const int seglen = TLEN / nseg;

    prep_w_k<<<(3 * HSD * CDIM + 255) / 256, 256, 0, stream>>>(Wq, Wk, Wv, Wt);
    if (use_xb){
        prep_x_k<<<(MROWS * CDIM) / (256 * 8), 256, 0, stream>>>(x, xb);
        proj_bf_k<<<MROWS / 16, 64, 0, stream>>>(xb, Wt, Qb, Kb, Vt);
    } else {
        proj_f32_k<<<MROWS / 16, 64, 0, stream>>>(x, Wt, Qb, Kb, Vt);
    }
    attn_k<<<dim3(TLEN / 64, nseg, BATCH), 256, 0, stream>>>(Qb, Kb, Vt, Opart, ml, seglen);
    merge_k<<<(MROWS * HSD) / 256, 256, 0, stream>>>(Opart, ml, out, nseg, seglen);
}

// Round 3
// 220.840 us; speedup vs baseline: 2.7421x; 1.4658x over previous
//
#include <hip/hip_runtime.h>
#include <hip/hip_bf16.h>

typedef __attribute__((ext_vector_type(8))) short short8;
typedef __attribute__((ext_vector_type(4))) float f32x4;

#define BATCH 4
#define TLEN 4096
#define CDIM 1024
#define HSD 128
#define MROWS (BATCH*TLEN)

__device__ __forceinline__ unsigned short f2bf(float f){
    unsigned u = __builtin_bit_cast(unsigned, f);
    u = (u + 0x7FFFu + ((u >> 16) & 1u)) >> 16;
    return (unsigned short)u;
}

// ---------------- kernel 1: W (C,HS) fp32 -> Wt (3,HS,C) bf16 ----------------
__global__ void prep_w_k(const float* __restrict__ Wq, const float* __restrict__ Wk,
                         const float* __restrict__ Wv, unsigned short* __restrict__ Wt){
    int idx = blockIdx.x * 256 + threadIdx.x;
    const int total = 3 * HSD * CDIM;
    if (idx >= total) return;
    int w = idx / (HSD * CDIM);
    int r = idx - w * HSD * CDIM;
    int h = r / CDIM;
    int c = r - h * CDIM;
    const float* W = (w == 0) ? Wq : ((w == 1) ? Wk : Wv);
    Wt[idx] = f2bf(W[c * HSD + h]);
}

// ---------------- kernel 1b: x fp32 -> bf16 ----------------
__global__ void prep_x_k(const float* __restrict__ x, unsigned short* __restrict__ xb){
    int i = (blockIdx.x * 256 + threadIdx.x) * 8;
    float4 a = *(const float4*)(x + i);
    float4 b = *(const float4*)(x + i + 4);
    short8 o;
    o[0]=(short)f2bf(a.x); o[1]=(short)f2bf(a.y); o[2]=(short)f2bf(a.z); o[3]=(short)f2bf(a.w);
    o[4]=(short)f2bf(b.x); o[5]=(short)f2bf(b.y); o[6]=(short)f2bf(b.z); o[7]=(short)f2bf(b.w);
    *(short8*)(xb + i) = o;
}

// ---------------- kernel 2: tiled projection GEMM (m97 structure) ----------------
// grid (M/128, 3), block 256 (4 waves). Block computes 128 rows x 128 cols of proj p.
// LDS tiles 128x32 bf16, double-buffered, staged via global_load_lds width 16 with
// lane-permuted global fetch (LDS slot linear in lane; XOR swizzle kills ds_read conflicts).
__device__ __forceinline__ void stage_tile32(unsigned short* buf, const unsigned short* g,
                                             int ldg, int tid){
#pragma unroll
    for (int i = 0; i < 2; i++){
        int c = i * 256 + tid;              // LDS chunk slot (linear: base + lane*16B)
        int row = c >> 2, kp = c & 3;
        int swz = (row & 3) ^ ((row >> 2) & 3);
        const unsigned short* gp = g + (size_t)row * ldg + ((kp ^ swz) << 3);
        unsigned short* lp = buf + (c << 3);
        __builtin_amdgcn_global_load_lds((const __attribute__((address_space(1))) void*)gp,
                                         (__attribute__((address_space(3))) void*)lp, 16, 0, 0);
    }
}

__global__ __launch_bounds__(256) void proj_k(const unsigned short* __restrict__ xb,
                                              const unsigned short* __restrict__ Wt,
                                              unsigned short* __restrict__ Qb,
                                              unsigned short* __restrict__ Kb,
                                              unsigned short* __restrict__ Vt){
    __shared__ unsigned short As[2][128 * 32];   // x rows
    __shared__ unsigned short Bs[2][128 * 32];   // W rows (output cols)

    const int tid = threadIdx.x, lane = tid & 63, wave = tid >> 6;
    const int m = lane & 15, quad = lane >> 4;
    const int wr = wave & 1, wc = wave >> 1;
    const int rb = blockIdx.x * 128;
    const int p  = blockIdx.y;

    const unsigned short* gA = xb + (size_t)rb * CDIM;
    const unsigned short* gB = Wt + (size_t)(p * HSD) * CDIM;

    f32x4 acc[4][4];
#pragma unroll
    for (int i = 0; i < 4; i++)
#pragma unroll
        for (int j = 0; j < 4; j++) acc[i][j] = (f32x4)0.f;

    stage_tile32(&As[0][0], gA, CDIM, tid);
    stage_tile32(&Bs[0][0], gB, CDIM, tid);
    __syncthreads();

    int cur = 0;
    for (int kc = 0; kc < CDIM / 32; ++kc){
        if (kc + 1 < CDIM / 32){
            stage_tile32(&As[cur ^ 1][0], gA + (kc + 1) * 32, CDIM, tid);
            stage_tile32(&Bs[cur ^ 1][0], gB + (kc + 1) * 32, CDIM, tid);
        }
        // orientation: p<2 -> A-side = W (h becomes D-row: packed Q/K stores)
        //              p==2 -> A-side = x (t becomes D-row: packed Vt stores)
        const unsigned short* Af = (p == 2) ? &As[cur][0] : &Bs[cur][0];
        const unsigned short* Bf = (p == 2) ? &Bs[cur][0] : &As[cur][0];
        short8 aF[4], bF[4];
#pragma unroll
        for (int i = 0; i < 4; i++){
            int ra = wr * 64 + i * 16 + m;
            int sa = (ra & 3) ^ ((ra >> 2) & 3);
            aF[i] = *(const short8*)&Af[ra * 32 + ((quad ^ sa) << 3)];
            int rn = wc * 64 + i * 16 + m;
            int sb = (rn & 3) ^ ((rn >> 2) & 3);
            bF[i] = *(const short8*)&Bf[rn * 32 + ((quad ^ sb) << 3)];
        }
#pragma unroll
        for (int i = 0; i < 4; i++)
#pragma unroll
            for (int j = 0; j < 4; j++)
                acc[i][j] = __builtin_amdgcn_mfma_f32_16x16x32_bf16(aF[i], bF[j], acc[i][j], 0, 0, 0);
        __syncthreads();
        cur ^= 1;
    }

    // ---- epilogue: packed ushort4 stores
    if (p < 2){
        unsigned short* D = (p == 0) ? Qb : Kb;
        // D-row = h (W side), D-col = t (x side); lane regs span 4 consecutive h
#pragma unroll
        for (int i = 0; i < 4; i++){
#pragma unroll
            for (int j = 0; j < 4; j++){
                int h = wr * 64 + i * 16 + quad * 4;
                int t = rb + wc * 64 + j * 16 + m;
                ushort4 v;
                v.x = f2bf(acc[i][j][0]); v.y = f2bf(acc[i][j][1]);
                v.z = f2bf(acc[i][j][2]); v.w = f2bf(acc[i][j][3]);
                *(ushort4*)(D + (size_t)t * HSD + h) = v;
            }
        }
    } else {
        // D-row = t (x side), D-col = h (W side); lane regs span 4 consecutive t
        int b = rb >> 12;
        int tb = rb & 4095;
#pragma unroll
        for (int i = 0; i < 4; i++){
#pragma unroll
            for (int j = 0; j < 4; j++){
                int t = tb + wr * 64 + i * 16 + quad * 4;
                int h = wc * 64 + j * 16 + m;
                ushort4 v;
                v.x = f2bf(acc[i][j][0]); v.y = f2bf(acc[i][j][1]);
                v.z = f2bf(acc[i][j][2]); v.w = f2bf(acc[i][j][3]);
                *(ushort4*)(Vt + ((size_t)b * HSD + h) * TLEN + t) = v;
            }
        }
    }
}

// ---------------- kernel 2b: projection fallback from fp32 x (small ws) ----------------
__global__ void proj_f32_k(const float* __restrict__ x, const unsigned short* __restrict__ Wt,
                           unsigned short* __restrict__ Qb, unsigned short* __restrict__ Kb,
                           unsigned short* __restrict__ Vt){
    const int lane = threadIdx.x;
    const int m = lane & 15, quad = lane >> 4;
    const int rb = blockIdx.x * 16;

    f32x4 acc[3][8];
#pragma unroll
    for (int p = 0; p < 3; p++)
#pragma unroll
        for (int i = 0; i < 8; i++) acc[p][i] = (f32x4)0.f;

    const float* xrow = x + (size_t)(rb + m) * CDIM + quad * 8;
    for (int k0 = 0; k0 < CDIM; k0 += 32){
        float4 a0 = *(const float4*)(xrow + k0);
        float4 a1 = *(const float4*)(xrow + k0 + 4);
        short8 aF;
        aF[0]=(short)f2bf(a0.x); aF[1]=(short)f2bf(a0.y); aF[2]=(short)f2bf(a0.z); aF[3]=(short)f2bf(a0.w);
        aF[4]=(short)f2bf(a1.x); aF[5]=(short)f2bf(a1.y); aF[6]=(short)f2bf(a1.z); aF[7]=(short)f2bf(a1.w);
#pragma unroll
        for (int p = 0; p < 3; p++){
#pragma unroll
            for (int sub = 0; sub < 8; sub++){
                short8 bF = *(const short8*)(Wt + (size_t)(p * HSD + sub * 16 + m) * CDIM + k0 + quad * 8);
                acc[p][sub] = __builtin_amdgcn_mfma_f32_16x16x32_bf16(aF, bF, acc[p][sub], 0, 0, 0);
            }
        }
    }
#pragma unroll
    for (int p = 0; p < 3; p++){
#pragma unroll
        for (int sub = 0; sub < 8; sub++){
#pragma unroll
            for (int r = 0; r < 4; r++){
                int row = rb + quad * 4 + r;
                int col = sub * 16 + m;
                unsigned short v = f2bf(acc[p][sub][r]);
                if (p == 0)      Qb[(size_t)row * HSD + col] = v;
                else if (p == 1) Kb[(size_t)row * HSD + col] = v;
                else {
                    int b = row >> 12;
                    int t = row & 4095;
                    Vt[((size_t)b * HSD + col) * TLEN + t] = v;
                }
            }
        }
    }
}

// ---------------- LDS staging for attention tiles ----------------
__device__ __forceinline__ void stage_k_tile(unsigned short* buf, const unsigned short* g,
                                             int wave, int lane){
#pragma unroll
    for (int i = 0; i < 4; i++){
        int slot = wave * 256 + i * 64 + lane;
        int row = slot >> 4;
        int ch  = slot & 15;
        const unsigned short* gp = g + row * 128 + ((ch ^ (row & 15)) << 3);
        unsigned short* lp = buf + ((wave * 256 + i * 64) << 3);
        __builtin_amdgcn_global_load_lds((const __attribute__((address_space(1))) void*)gp,
                                         (__attribute__((address_space(3))) void*)lp, 16, 0, 0);
    }
}
__device__ __forceinline__ void stage_v_tile(unsigned short* buf, const unsigned short* g,
                                             int wave, int lane){
#pragma unroll
    for (int i = 0; i < 4; i++){
        int slot = wave * 256 + i * 64 + lane;
        int row = slot >> 3;
        int ch  = slot & 7;
        const unsigned short* gp = g + (size_t)row * TLEN + ((ch ^ (row & 7)) << 3);
        unsigned short* lp = buf + ((wave * 256 + i * 64) << 3);
        __builtin_amdgcn_global_load_lds((const __attribute__((address_space(1))) void*)gp,
                                         (__attribute__((address_space(3))) void*)lp, 16, 0, 0);
    }
}

// ---------------- kernel 3: causal flash attention, split-K partials ----------------
__global__ __launch_bounds__(256) void attn_k(const unsigned short* __restrict__ Qb,
                       const unsigned short* __restrict__ Kb,
                       const unsigned short* __restrict__ Vts,
                       float* __restrict__ Opart, float2* __restrict__ ml, int seglen){
    __shared__ unsigned short Kt[2][64 * 128];
    __shared__ unsigned short Vs[2][128 * 64];
    __shared__ unsigned short Pl[4][16 * 72];

    const int tid = threadIdx.x, lane = tid & 63, wave = tid >> 6;
    const int m = lane & 15, quad = lane >> 4;
    const int q0 = blockIdx.x * 64;
    const int seg = blockIdx.y, b = blockIdx.z;
    const int g0 = seg * seglen;
    if (g0 >= q0 + 64) return;
    const int gend = min(g0 + seglen, q0 + 64);
    const int nT = (gend - g0) >> 6;
    const float scale = 0.08838834764831845f;

    const size_t rowg = (size_t)b * TLEN + q0 + wave * 16;

    short8 aQ[4];
#pragma unroll
    for (int kk = 0; kk < 4; kk++)
        aQ[kk] = *(const short8*)(Qb + (rowg + m) * HSD + kk * 32 + quad * 8);

    f32x4 accO[8];
#pragma unroll
    for (int i = 0; i < 8; i++) accO[i] = (f32x4)0.f;
    float mi[4], li[4];
#pragma unroll
    for (int r = 0; r < 4; r++){ mi[r] = -1e30f; li[r] = 0.f; }

    const unsigned short* kbase = Kb + (size_t)b * TLEN * HSD;
    const unsigned short* vbase = Vts + (size_t)b * HSD * TLEN;

    stage_k_tile(&Kt[0][0], kbase + (size_t)g0 * HSD, wave, lane);
    stage_v_tile(&Vs[0][0], vbase + g0, wave, lane);
    __syncthreads();

    int cur = 0;
    for (int t = 0; t < nT; ++t){
        const int s0 = g0 + t * 64;
        if (t + 1 < nT){
            stage_k_tile(&Kt[cur ^ 1][0], kbase + (size_t)(s0 + 64) * HSD, wave, lane);
            stage_v_tile(&Vs[cur ^ 1][0], vbase + (s0 + 64), wave, lane);
        }
        f32x4 S[4];
#pragma unroll
        for (int ns = 0; ns < 4; ns++){
            f32x4 sa = (f32x4)0.f;
#pragma unroll
            for (int kk = 0; kk < 4; kk++){
                short8 bK = *(const short8*)&Kt[cur][(ns * 16 + m) * 128 + (((kk * 4 + quad) ^ m) << 3)];
                sa = __builtin_amdgcn_mfma_f32_16x16x32_bf16(aQ[kk], bK, sa, 0, 0, 0);
            }
#pragma unroll
            for (int r = 0; r < 4; r++) sa[r] *= scale;
            S[ns] = sa;
        }
        if (s0 + 63 > q0 + wave * 16){
#pragma unroll
            for (int ns = 0; ns < 4; ns++){
                int sg = s0 + ns * 16 + m;
#pragma unroll
                for (int r = 0; r < 4; r++){
                    int qrow = q0 + wave * 16 + quad * 4 + r;
                    if (sg > qrow) S[ns][r] = -1e30f;
                }
            }
        }
        float mloc[4];
#pragma unroll
        for (int r = 0; r < 4; r++)
            mloc[r] = fmaxf(fmaxf(S[0][r], S[1][r]), fmaxf(S[2][r], S[3][r]));
#pragma unroll
        for (int off = 1; off < 16; off <<= 1)
#pragma unroll
            for (int r = 0; r < 4; r++)
                mloc[r] = fmaxf(mloc[r], __shfl_xor(mloc[r], off, 64));
        float al[4];
#pragma unroll
        for (int r = 0; r < 4; r++){
            float mn = fmaxf(mi[r], mloc[r]);
            al[r] = __expf(mi[r] - mn);
            mi[r] = mn;
        }
        float lsum[4] = {0.f, 0.f, 0.f, 0.f};
#pragma unroll
        for (int ns = 0; ns < 4; ns++){
#pragma unroll
            for (int r = 0; r < 4; r++){
                float pv = __expf(S[ns][r] - mi[r]);
                lsum[r] += pv;
                Pl[wave][(quad * 4 + r) * 72 + ns * 16 + m] = f2bf(pv);
            }
        }
#pragma unroll
        for (int off = 1; off < 16; off <<= 1)
#pragma unroll
            for (int r = 0; r < 4; r++)
                lsum[r] += __shfl_xor(lsum[r], off, 64);
#pragma unroll
        for (int r = 0; r < 4; r++) li[r] = li[r] * al[r] + lsum[r];
#pragma unroll
        for (int sub = 0; sub < 8; sub++)
#pragma unroll
            for (int r = 0; r < 4; r++) accO[sub][r] *= al[r];
        short8 aP[2];
#pragma unroll
        for (int t2 = 0; t2 < 2; t2++)
            aP[t2] = *(const short8*)&Pl[wave][m * 72 + t2 * 32 + quad * 8];
#pragma unroll
        for (int sub = 0; sub < 8; sub++){
#pragma unroll
            for (int t2 = 0; t2 < 2; t2++){
                short8 bV = *(const short8*)&Vs[cur][(sub * 16 + m) * 64 + (((t2 * 4 + quad) ^ (m & 7)) << 3)];
                accO[sub] = __builtin_amdgcn_mfma_f32_16x16x32_bf16(aP[t2], bV, accO[sub], 0, 0, 0);
            }
        }
        __syncthreads();
        cur ^= 1;
    }
    if (m == 0){
#pragma unroll
        for (int r = 0; r < 4; r++){
            float2 v; v.x = mi[r]; v.y = li[r];
            ml[(size_t)seg * MROWS + rowg + quad * 4 + r] = v;
        }
    }
    float* ob = Opart + (size_t)seg * MROWS * HSD;
#pragma unroll
    for (int sub = 0; sub < 8; sub++)
#pragma unroll
        for (int r = 0; r < 4; r++)
            ob[(rowg + quad * 4 + r) * HSD + sub * 16 + m] = accO[sub][r];
}

// ---------------- kernel 4: merge split-K partials ----------------
__global__ void merge_k(const float* __restrict__ Opart, const float2* __restrict__ ml,
                        float* __restrict__ out, int nseg, int seglen){
    int idx = blockIdx.x * 256 + threadIdx.x;
    int row = idx >> 7;
    int t = row & (TLEN - 1);
    int q0 = t & ~63;
    int nsv = min(nseg, (q0 + 63) / seglen + 1);
    float M = -1e30f;
    for (int s = 0; s < nsv; s++) M = fmaxf(M, ml[(size_t)s * MROWS + row].x);
    float L = 0.f, o = 0.f;
    for (int s = 0; s < nsv; s++){
        float2 p = ml[(size_t)s * MROWS + row];
        float w = __expf(p.x - M);
        L += p.y * w;
        o += w * Opart[(size_t)s * MROWS * HSD + idx];
    }
    out[idx] = o / L;
}

extern "C" void kernel_launch(void* const* d_in, const int* in_sizes, int n_in,
                              void* d_out, int out_size, void* d_ws, size_t ws_size,
                              hipStream_t stream) {
    const float* x  = (const float*)d_in[0];
    const float* Wq = (const float*)d_in[1];
    const float* Wk = (const float*)d_in[2];
    const float* Wv = (const float*)d_in[3];
    float* out = (float*)d_out;
    char* w = (char*)d_ws;

    unsigned short* Wt = (unsigned short*)w;    // 768 KB @ 0
    unsigned short *xb = nullptr, *Qb, *Kb, *Vt;
    float* Opart; float2* ml;
    int nseg; bool use_xb;

    if (ws_size >= (size_t)78u * 1024 * 1024){
        nseg = 4; use_xb = true;
        xb = (unsigned short*)(w + ((size_t)1u  << 20));
        Qb = (unsigned short*)(w + ((size_t)33u << 20));
        Kb = (unsigned short*)(w + ((size_t)37u << 20));
        Vt = (unsigned short*)(w + ((size_t)41u << 20));
        Opart = (float*)(w + ((size_t)45u << 20));
        ml    = (float2*)(w + ((size_t)77u << 20));
    } else if (ws_size >= (size_t)46u * 1024 * 1024){
        nseg = 1; use_xb = true;
        xb = (unsigned short*)(w + ((size_t)1u  << 20));
        Qb = (unsigned short*)(w + ((size_t)33u << 20));
        Kb = (unsigned short*)(w + ((size_t)37u << 20));
        Vt = (unsigned short*)(w + ((size_t)41u << 20));
        Opart = out;
        ml    = (float2*)(w + ((size_t)45u << 20));
    } else {
        nseg = 1; use_xb = false;
        Qb = (unsigned short*)(w + ((size_t)1u << 20));
        Kb = (unsigned short*)(w + ((size_t)5u << 20));
        Vt = (unsigned short*)(w + ((size_t)9u << 20));
        Opart = out;
        ml    = (float2*)(w + ((size_t)13u << 20));
    }
    const int seglen = TLEN / nseg;

    prep_w_k<<<(3 * HSD * CDIM + 255) / 256, 256, 0, stream>>>(Wq, Wk, Wv, Wt);
    if (use_xb){
        prep_x_k<<<(MROWS * CDIM) / (256 * 8), 256, 0, stream>>>(x, xb);
        proj_k<<<dim3(MROWS / 128, 3), 256, 0, stream>>>(xb, Wt, Qb, Kb, Vt);
    } else {
        proj_f32_k<<<MROWS / 16, 64, 0, stream>>>(x, Wt, Qb, Kb, Vt);
    }
    attn_k<<<dim3(TLEN / 64, nseg, BATCH), 256, 0, stream>>>(Qb, Kb, Vt, Opart, ml, seglen);
    merge_k<<<(MROWS * HSD) / 256, 256, 0, stream>>>(Opart, ml, out, nseg, seglen);
}

// Round 5
// 214.101 us; speedup vs baseline: 2.8284x; 1.0315x over previous
//
#include <hip/hip_runtime.h>
#include <hip/hip_bf16.h>

typedef __attribute__((ext_vector_type(8))) short short8;
typedef __attribute__((ext_vector_type(4))) short s4v;
typedef __attribute__((ext_vector_type(4))) float f32x4;

#define BATCH 4
#define TLEN 4096
#define CDIM 1024
#define HSD 128
#define MROWS (BATCH*TLEN)

// 1/sqrt(128) * log2(e): fold into Q so softmax runs in exp2 domain
#define QSCALE 0.12751744f

// K=16 bf16 MFMA (gfx90a-lineage name, present on gfx950). Host pass must
// still parse device code, so give it a type-correct no-op.
#ifdef __HIP_DEVICE_COMPILE__
  #define MFMA16(a,b,c) __builtin_amdgcn_mfma_f32_16x16x16bf16_1k(a,b,c,0,0,0)
#else
  #define MFMA16(a,b,c) (c)
#endif

__device__ __forceinline__ unsigned short f2bf(float f){
    unsigned u = __builtin_bit_cast(unsigned, f);
    u = (u + 0x7FFFu + ((u >> 16) & 1u)) >> 16;
    return (unsigned short)u;
}
// pack 2 f32 -> 2 bf16 in a dword (round-half-up; inputs are P in [0,1])
__device__ __forceinline__ unsigned pkbf(float a, float b){
    unsigned ua = (__builtin_bit_cast(unsigned, a) + 0x8000u) >> 16;
    unsigned ub = (__builtin_bit_cast(unsigned, b) + 0x8000u) & 0xFFFF0000u;
    return ua | ub;
}

// ---------------- kernel 1: W (C,HS) fp32 -> Wt (3,HS,C) bf16 ----------------
__global__ void prep_w_k(const float* __restrict__ Wq, const float* __restrict__ Wk,
                         const float* __restrict__ Wv, unsigned short* __restrict__ Wt){
    int idx = blockIdx.x * 256 + threadIdx.x;
    const int total = 3 * HSD * CDIM;
    if (idx >= total) return;
    int w = idx / (HSD * CDIM);
    int r = idx - w * HSD * CDIM;
    int h = r / CDIM;
    int c = r - h * CDIM;
    const float* W = (w == 0) ? Wq : ((w == 1) ? Wk : Wv);
    Wt[idx] = f2bf(W[c * HSD + h]);
}

// ---------------- kernel 1b: x fp32 -> bf16 ----------------
__global__ void prep_x_k(const float* __restrict__ x, unsigned short* __restrict__ xb){
    int i = (blockIdx.x * 256 + threadIdx.x) * 8;
    float4 a = *(const float4*)(x + i);
    float4 b = *(const float4*)(x + i + 4);
    short8 o;
    o[0]=(short)f2bf(a.x); o[1]=(short)f2bf(a.y); o[2]=(short)f2bf(a.z); o[3]=(short)f2bf(a.w);
    o[4]=(short)f2bf(b.x); o[5]=(short)f2bf(b.y); o[6]=(short)f2bf(b.z); o[7]=(short)f2bf(b.w);
    *(short8*)(xb + i) = o;
}

// ---------------- kernel 2: tiled projection GEMM ----------------
__device__ __forceinline__ void stage_tile32(unsigned short* buf, const unsigned short* g,
                                             int ldg, int tid){
#pragma unroll
    for (int i = 0; i < 2; i++){
        int c = i * 256 + tid;
        int row = c >> 2, kp = c & 3;
        int swz = (row & 3) ^ ((row >> 2) & 3);
        const unsigned short* gp = g + (size_t)row * ldg + ((kp ^ swz) << 3);
        unsigned short* lp = buf + (c << 3);
        __builtin_amdgcn_global_load_lds((const __attribute__((address_space(1))) void*)gp,
                                         (__attribute__((address_space(3))) void*)lp, 16, 0, 0);
    }
}

__global__ __launch_bounds__(256) void proj_k(const unsigned short* __restrict__ xb,
                                              const unsigned short* __restrict__ Wt,
                                              unsigned short* __restrict__ Qb,
                                              unsigned short* __restrict__ Kb,
                                              unsigned short* __restrict__ Vt){
    __shared__ unsigned short As[2][128 * 32];
    __shared__ unsigned short Bs[2][128 * 32];

    const int tid = threadIdx.x, lane = tid & 63, wave = tid >> 6;
    const int m = lane & 15, quad = lane >> 4;
    const int wr = wave & 1, wc = wave >> 1;
    const int rb = blockIdx.x * 128;
    const int p  = blockIdx.y;

    const unsigned short* gA = xb + (size_t)rb * CDIM;
    const unsigned short* gB = Wt + (size_t)(p * HSD) * CDIM;

    f32x4 acc[4][4];
#pragma unroll
    for (int i = 0; i < 4; i++)
#pragma unroll
        for (int j = 0; j < 4; j++) acc[i][j] = (f32x4)0.f;

    stage_tile32(&As[0][0], gA, CDIM, tid);
    stage_tile32(&Bs[0][0], gB, CDIM, tid);
    __syncthreads();

    int cur = 0;
    for (int kc = 0; kc < CDIM / 32; ++kc){
        if (kc + 1 < CDIM / 32){
            stage_tile32(&As[cur ^ 1][0], gA + (kc + 1) * 32, CDIM, tid);
            stage_tile32(&Bs[cur ^ 1][0], gB + (kc + 1) * 32, CDIM, tid);
        }
        const unsigned short* Af = (p == 2) ? &As[cur][0] : &Bs[cur][0];
        const unsigned short* Bf = (p == 2) ? &Bs[cur][0] : &As[cur][0];
        short8 aF[4], bF[4];
#pragma unroll
        for (int i = 0; i < 4; i++){
            int ra = wr * 64 + i * 16 + m;
            int sa = (ra & 3) ^ ((ra >> 2) & 3);
            aF[i] = *(const short8*)&Af[ra * 32 + ((quad ^ sa) << 3)];
            int rn = wc * 64 + i * 16 + m;
            int sb = (rn & 3) ^ ((rn >> 2) & 3);
            bF[i] = *(const short8*)&Bf[rn * 32 + ((quad ^ sb) << 3)];
        }
#pragma unroll
        for (int i = 0; i < 4; i++)
#pragma unroll
            for (int j = 0; j < 4; j++)
                acc[i][j] = __builtin_amdgcn_mfma_f32_16x16x32_bf16(aF[i], bF[j], acc[i][j], 0, 0, 0);
        __syncthreads();
        cur ^= 1;
    }

    if (p < 2){
        unsigned short* D = (p == 0) ? Qb : Kb;
        const float qs = (p == 0) ? QSCALE : 1.0f;
#pragma unroll
        for (int i = 0; i < 4; i++){
#pragma unroll
            for (int j = 0; j < 4; j++){
                int h = wr * 64 + i * 16 + quad * 4;
                int t = rb + wc * 64 + j * 16 + m;
                ushort4 v;
                v.x = f2bf(acc[i][j][0] * qs); v.y = f2bf(acc[i][j][1] * qs);
                v.z = f2bf(acc[i][j][2] * qs); v.w = f2bf(acc[i][j][3] * qs);
                *(ushort4*)(D + (size_t)t * HSD + h) = v;
            }
        }
    } else {
        int b = rb >> 12;
        int tb = rb & 4095;
#pragma unroll
        for (int i = 0; i < 4; i++){
#pragma unroll
            for (int j = 0; j < 4; j++){
                int t = tb + wr * 64 + i * 16 + quad * 4;
                int h = wc * 64 + j * 16 + m;
                ushort4 v;
                v.x = f2bf(acc[i][j][0]); v.y = f2bf(acc[i][j][1]);
                v.z = f2bf(acc[i][j][2]); v.w = f2bf(acc[i][j][3]);
                *(ushort4*)(Vt + ((size_t)b * HSD + h) * TLEN + t) = v;
            }
        }
    }
}

// ---------------- kernel 2b: projection fallback from fp32 x ----------------
__global__ void proj_f32_k(const float* __restrict__ x, const unsigned short* __restrict__ Wt,
                           unsigned short* __restrict__ Qb, unsigned short* __restrict__ Kb,
                           unsigned short* __restrict__ Vt){
    const int lane = threadIdx.x;
    const int m = lane & 15, quad = lane >> 4;
    const int rb = blockIdx.x * 16;

    f32x4 acc[3][8];
#pragma unroll
    for (int p = 0; p < 3; p++)
#pragma unroll
        for (int i = 0; i < 8; i++) acc[p][i] = (f32x4)0.f;

    const float* xrow = x + (size_t)(rb + m) * CDIM + quad * 8;
    for (int k0 = 0; k0 < CDIM; k0 += 32){
        float4 a0 = *(const float4*)(xrow + k0);
        float4 a1 = *(const float4*)(xrow + k0 + 4);
        short8 aF;
        aF[0]=(short)f2bf(a0.x); aF[1]=(short)f2bf(a0.y); aF[2]=(short)f2bf(a0.z); aF[3]=(short)f2bf(a0.w);
        aF[4]=(short)f2bf(a1.x); aF[5]=(short)f2bf(a1.y); aF[6]=(short)f2bf(a1.z); aF[7]=(short)f2bf(a1.w);
#pragma unroll
        for (int p = 0; p < 3; p++){
#pragma unroll
            for (int sub = 0; sub < 8; sub++){
                short8 bF = *(const short8*)(Wt + (size_t)(p * HSD + sub * 16 + m) * CDIM + k0 + quad * 8);
                acc[p][sub] = __builtin_amdgcn_mfma_f32_16x16x32_bf16(aF, bF, acc[p][sub], 0, 0, 0);
            }
        }
    }
#pragma unroll
    for (int p = 0; p < 3; p++){
        const float qs = (p == 0) ? QSCALE : 1.0f;
#pragma unroll
        for (int sub = 0; sub < 8; sub++){
#pragma unroll
            for (int r = 0; r < 4; r++){
                int row = rb + quad * 4 + r;
                int col = sub * 16 + m;
                unsigned short v = f2bf(acc[p][sub][r] * qs);
                if (p == 0)      Qb[(size_t)row * HSD + col] = v;
                else if (p == 1) Kb[(size_t)row * HSD + col] = v;
                else {
                    int b = row >> 12;
                    int t = row & 4095;
                    Vt[((size_t)b * HSD + col) * TLEN + t] = v;
                }
            }
        }
    }
}

// ---------------- attention LDS staging (single-buffered) ----------------
__device__ __forceinline__ void stage_k_tile(unsigned short* buf, const unsigned short* g,
                                             int wave, int lane){
#pragma unroll
    for (int i = 0; i < 4; i++){
        int slot = wave * 256 + i * 64 + lane;
        int row = slot >> 4;
        int ch  = slot & 15;
        const unsigned short* gp = g + row * 128 + ((ch ^ (row & 15)) << 3);
        unsigned short* lp = buf + (slot << 3);
        __builtin_amdgcn_global_load_lds((const __attribute__((address_space(1))) void*)gp,
                                         (__attribute__((address_space(3))) void*)lp, 16, 0, 0);
    }
}
__device__ __forceinline__ void stage_v_tile(unsigned short* buf, const unsigned short* g,
                                             int wave, int lane){
#pragma unroll
    for (int i = 0; i < 4; i++){
        int slot = wave * 256 + i * 64 + lane;
        int row = slot >> 3;
        int ch  = slot & 7;
        const unsigned short* gp = g + (size_t)row * TLEN + ((ch ^ (row & 7)) << 3);
        unsigned short* lp = buf + (slot << 3);
        __builtin_amdgcn_global_load_lds((const __attribute__((address_space(1))) void*)gp,
                                         (__attribute__((address_space(3))) void*)lp, 16, 0, 0);
    }
}

// ---------------- kernel 3: causal flash attention, S^T layout, split-K ----------------
// grid (T/64, nseg, B), block 256. Each lane owns softmax state of ONE query row (q = lane&15).
__global__ __launch_bounds__(256, 4) void attn_k(const unsigned short* __restrict__ Qb,
                       const unsigned short* __restrict__ Kb,
                       const unsigned short* __restrict__ Vts,
                       float* __restrict__ Opart, float2* __restrict__ ml, int seglen){
    __shared__ unsigned short Kt[64 * 128];   // 16 KB
    __shared__ unsigned short Vs[128 * 64];   // 16 KB

    const int tid = threadIdx.x, lane = tid & 63, wave = tid >> 6;
    const int m = lane & 15, quad = lane >> 4;
    const int q0 = ((int)gridDim.x - 1 - (int)blockIdx.x) * 64;   // long blocks first
    const int seg = blockIdx.y, b = blockIdx.z;
    const int g0 = seg * seglen;
    if (g0 >= q0 + 64) return;
    const int gend = min(g0 + seglen, q0 + 64);
    const int nT = (gend - g0) >> 6;

    const int q0w = q0 + wave * 16;
    const size_t rowg = (size_t)b * TLEN + q0w;

    // Q as B-frag (Q pre-scaled by 1/sqrt(d)*log2e at projection)
    short8 aQ[4];
#pragma unroll
    for (int kk = 0; kk < 4; kk++)
        aQ[kk] = *(const short8*)(Qb + (rowg + m) * HSD + kk * 32 + quad * 8);

    f32x4 accO[8];
#pragma unroll
    for (int i = 0; i < 8; i++) accO[i] = (f32x4)0.f;
    float mi = -1e30f, li = 0.f;      // per-lane: query row q = m

    const unsigned short* kbase = Kb + (size_t)b * TLEN * HSD;
    const unsigned short* vbase = Vts + (size_t)b * HSD * TLEN;
    const int bpbase = (lane >> 4) << 4;  // ds_bpermute byte addr of lane 4*quad

    for (int t = 0; t < nT; ++t){
        const int s0 = g0 + t * 64;
        stage_k_tile(&Kt[0], kbase + (size_t)s0 * HSD, wave, lane);
        stage_v_tile(&Vs[0], vbase + s0, wave, lane);
        __syncthreads();

        // ---- S^T = K Q^T : subtile ns rows s=16ns+4quad+r, col q=m
        f32x4 S[4];
#pragma unroll
        for (int ns = 0; ns < 4; ns++){
            f32x4 sa = (f32x4)0.f;
#pragma unroll
            for (int kk = 0; kk < 4; kk++){
                short8 bK = *(const short8*)&Kt[(ns * 16 + m) * 128 + (((kk * 4 + quad) ^ m) << 3)];
                sa = __builtin_amdgcn_mfma_f32_16x16x32_bf16(bK, aQ[kk], sa, 0, 0, 0);
            }
            S[ns] = sa;
        }
        // ---- causal mask (s > q)
        if (s0 + 63 > q0w){
            int qg = q0w + m;
#pragma unroll
            for (int ns = 0; ns < 4; ns++){
#pragma unroll
                for (int r = 0; r < 4; r++){
                    int sg = s0 + ns * 16 + quad * 4 + r;
                    if (sg > qg) S[ns][r] = -1e30f;
                }
            }
        }
        // ---- lane-local softmax (row q=m), cross-quad combine = 2 shuffles
        f32x4 m4 = S[0];
#pragma unroll
        for (int ns = 1; ns < 4; ns++)
#pragma unroll
            for (int r = 0; r < 4; r++) m4[r] = fmaxf(m4[r], S[ns][r]);
        float mloc = fmaxf(fmaxf(m4[0], m4[1]), fmaxf(m4[2], m4[3]));
        mloc = fmaxf(mloc, __shfl_xor(mloc, 16, 64));
        mloc = fmaxf(mloc, __shfl_xor(mloc, 32, 64));
        float mn = fmaxf(mi, mloc);
        float al = exp2f(mi - mn);
        mi = mn;

        float ps[4][4];
        float lsum = 0.f;
#pragma unroll
        for (int ns = 0; ns < 4; ns++)
#pragma unroll
            for (int r = 0; r < 4; r++){
                float pv = exp2f(S[ns][r] - mi);
                ps[ns][r] = pv;
                lsum += pv;
            }
        lsum += __shfl_xor(lsum, 16, 64);
        lsum += __shfl_xor(lsum, 32, 64);
        li = li * al + lsum;

        // ---- P -> bf16 A-frags of 16x16x16 (zero data movement)
        s4v aP[4];
#pragma unroll
        for (int ns = 0; ns < 4; ns++){
            uint2 u;
            u.x = pkbf(ps[ns][0], ps[ns][1]);
            u.y = pkbf(ps[ns][2], ps[ns][3]);
            aP[ns] = __builtin_bit_cast(s4v, u);
        }
        // ---- rescale accO: row q = 4*quad+r needs al of lane m=4*quad+r
        float alr[4];
#pragma unroll
        for (int r = 0; r < 4; r++)
            alr[r] = __builtin_bit_cast(float,
                __builtin_amdgcn_ds_bpermute(bpbase + 4 * r, __builtin_bit_cast(int, al)));
#pragma unroll
        for (int sub = 0; sub < 8; sub++)
#pragma unroll
            for (int r = 0; r < 4; r++) accO[sub][r] *= alr[r];
        // ---- O += P V   (B-frag: V[s=16ns+4quad+j][h=16sub+m] from swizzled Vs)
#pragma unroll
        for (int sub = 0; sub < 8; sub++){
#pragma unroll
            for (int ns = 0; ns < 4; ns++){
                s4v bV = *(const s4v*)&Vs[(sub * 16 + m) * 64 +
                        (((2 * ns + (quad >> 1)) ^ (m & 7)) << 3) + (quad & 1) * 4];
                accO[sub] = MFMA16(aP[ns], bV, accO[sub]);
            }
        }
        __syncthreads();
    }
    // ---- epilogue: (m,l) per row from quad-0 lanes; unnormalized O partial
    if (quad == 0){
        float2 v; v.x = mi; v.y = li;
        ml[(size_t)seg * MROWS + rowg + m] = v;
    }
    float* ob = Opart + (size_t)seg * MROWS * HSD;
#pragma unroll
    for (int sub = 0; sub < 8; sub++)
#pragma unroll
        for (int r = 0; r < 4; r++)
            ob[(rowg + quad * 4 + r) * HSD + sub * 16 + m] = accO[sub][r];
}

// ---------------- kernel 4: merge split-K partials (exp2 domain) ----------------
__global__ void merge_k(const float* __restrict__ Opart, const float2* __restrict__ ml,
                        float* __restrict__ out, int nseg, int seglen){
    int idx = blockIdx.x * 256 + threadIdx.x;
    int row = idx >> 7;
    int t = row & (TLEN - 1);
    int q0 = t & ~63;
    int nsv = min(nseg, (q0 + 63) / seglen + 1);
    float M = -1e30f;
    for (int s = 0; s < nsv; s++) M = fmaxf(M, ml[(size_t)s * MROWS + row].x);
    float L = 0.f, o = 0.f;
    for (int s = 0; s < nsv; s++){
        float2 p = ml[(size_t)s * MROWS + row];
        float w = exp2f(p.x - M);
        L += p.y * w;
        o += w * Opart[(size_t)s * MROWS * HSD + idx];
    }
    out[idx] = o / L;
}

extern "C" void kernel_launch(void* const* d_in, const int* in_sizes, int n_in,
                              void* d_out, int out_size, void* d_ws, size_t ws_size,
                              hipStream_t stream) {
    const float* x  = (const float*)d_in[0];
    const float* Wq = (const float*)d_in[1];
    const float* Wk = (const float*)d_in[2];
    const float* Wv = (const float*)d_in[3];
    float* out = (float*)d_out;
    char* w = (char*)d_ws;

    unsigned short* Wt = (unsigned short*)w;
    unsigned short *xb = nullptr, *Qb, *Kb, *Vt;
    float* Opart; float2* ml;
    int nseg; bool use_xb;

    if (ws_size >= (size_t)78u * 1024 * 1024){
        nseg = 4; use_xb = true;
        xb = (unsigned short*)(w + ((size_t)1u  << 20));
        Qb = (unsigned short*)(w + ((size_t)33u << 20));
        Kb = (unsigned short*)(w + ((size_t)37u << 20));
        Vt = (unsigned short*)(w + ((size_t)41u << 20));
        Opart = (float*)(w + ((size_t)45u << 20));
        ml    = (float2*)(w + ((size_t)77u << 20));
    } else if (ws_size >= (size_t)46u * 1024 * 1024){
        nseg = 1; use_xb = true;
        xb = (unsigned short*)(w + ((size_t)1u  << 20));
        Qb = (unsigned short*)(w + ((size_t)33u << 20));
        Kb = (unsigned short*)(w + ((size_t)37u << 20));
        Vt = (unsigned short*)(w + ((size_t)41u << 20));
        Opart = out;
        ml    = (float2*)(w + ((size_t)45u << 20));
    } else {
        nseg = 1; use_xb = false;
        Qb = (unsigned short*)(w + ((size_t)1u << 20));
        Kb = (unsigned short*)(w + ((size_t)5u << 20));
        Vt = (unsigned short*)(w + ((size_t)9u << 20));
        Opart = out;
        ml    = (float2*)(w + ((size_t)13u << 20));
    }
    const int seglen = TLEN / nseg;

    prep_w_k<<<(3 * HSD * CDIM + 255) / 256, 256, 0, stream>>>(Wq, Wk, Wv, Wt);
    if (use_xb){
        prep_x_k<<<(MROWS * CDIM) / (256 * 8), 256, 0, stream>>>(x, xb);
        proj_k<<<dim3(MROWS / 128, 3), 256, 0, stream>>>(xb, Wt, Qb, Kb, Vt);
    } else {
        proj_f32_k<<<MROWS / 16, 64, 0, stream>>>(x, Wt, Qb, Kb, Vt);
    }
    attn_k<<<dim3(TLEN / 64, nseg, BATCH), 256, 0, stream>>>(Qb, Kb, Vt, Opart, ml, seglen);
    merge_k<<<(MROWS * HSD) / 256, 256, 0, stream>>>(Opart, ml, out, nseg, seglen);
}